// Round 4
// baseline (807.257 us; speedup 1.0000x reference)
//
#include <hip/hip_runtime.h>
#include <hip/hip_bf16.h>
#include <hip/hip_fp16.h>

// GCN: 3 layers of  h = relu(in_norm * A_pull( (out_norm*x) @ W ) + b)
// then seg_output = (mean_n h3) @ Wp^T + bp  and  CAM = Wp @ h3^T.
// CSR built per call. Degree histograms are privatized PER XCD and updated
// with workgroup-scope atomics -> resolved in the local XCD L2 (no MALL
// round-trip). Per-edge rank (within its XCD partial) + xcd id recorded in
// pos; a per-node scan over the 8 partials gives global slots -> fill is
// atomic-free. Layers 1-2 use fp16 gather tensor; layer 3 fp32.

#define HDIM 128
#define NCLS 40
#define NXCD 8

__device__ __forceinline__ unsigned get_xcc_id() {
    unsigned x;
    asm volatile("s_getreg_b32 %0, hwreg(20, 0, 32)" : "=s"(x));  // HW_REG_XCC_ID
    return x & 7u;
}

// ---------------- graph preprocessing ----------------

__global__ void zero4_kernel(int4* __restrict__ p, int n4) {
    int i = blockIdx.x * blockDim.x + threadIdx.x;
    if (i < n4) { int4 z = {0, 0, 0, 0}; p[i] = z; }
}

// Per-XCD privatized histograms, workgroup-scope atomics (L2-resolved).
__global__ void deg_kernel(const int* __restrict__ src, const int* __restrict__ dst,
                           unsigned* __restrict__ hist_out, unsigned* __restrict__ hist_in,
                           int* __restrict__ posx, int N, int E) {
    const unsigned x = get_xcc_id();
    unsigned* ho = hist_out + (size_t)x * N;
    unsigned* hi = hist_in + (size_t)x * N;
    int i = blockIdx.x * blockDim.x + threadIdx.x;
    if (i < E) {
        __hip_atomic_fetch_add(&ho[src[i]], 1u, __ATOMIC_RELAXED, __HIP_MEMORY_SCOPE_WORKGROUP);
        unsigned r = __hip_atomic_fetch_add(&hi[dst[i]], 1u, __ATOMIC_RELAXED, __HIP_MEMORY_SCOPE_WORKGROUP);
        posx[i] = (int)(r | (x << 24));
    }
}

// Per node: exclusive scan over the 8 XCD partials -> xoff, totals -> degrees/norms.
__global__ void xcdscan_kernel(const unsigned* __restrict__ hist_out,
                               const unsigned* __restrict__ hist_in,
                               unsigned* __restrict__ xoff, int* __restrict__ in_deg,
                               float* __restrict__ out_norm, float* __restrict__ in_norm, int N) {
    int n = blockIdx.x * blockDim.x + threadIdx.x;
    if (n >= N) return;
    unsigned acc = 0;
    #pragma unroll
    for (int x = 0; x < NXCD; ++x) {
        unsigned c = hist_in[(size_t)x * N + n];
        xoff[(size_t)x * N + n] = acc;
        acc += c;
    }
    in_deg[n] = (int)acc;
    unsigned od = 0;
    #pragma unroll
    for (int x = 0; x < NXCD; ++x) od += hist_out[(size_t)x * N + n];
    out_norm[n] = 1.0f / sqrtf((float)max(od, 1u));
    in_norm[n]  = 1.0f / sqrtf((float)max(acc, 1u));
}

// ---- 3-pass exclusive scan over in_deg -> row_ptr ----

__global__ void scan_part_kernel(const int* __restrict__ cnt, int* __restrict__ bsum, int n) {
    const int tid = threadIdx.x;
    int base = blockIdx.x * 1024 + tid * 4;
    int s = 0;
    #pragma unroll
    for (int j = 0; j < 4; ++j) if (base + j < n) s += cnt[base + j];
    #pragma unroll
    for (int d = 1; d < 64; d <<= 1) s += __shfl_down(s, d, 64);
    __shared__ int ws[4];
    if ((tid & 63) == 0) ws[tid >> 6] = s;
    __syncthreads();
    if (tid == 0) bsum[blockIdx.x] = ws[0] + ws[1] + ws[2] + ws[3];
}

__global__ void scan_mid_kernel(const int* __restrict__ bsum, int* __restrict__ psum,
                                int* __restrict__ row_ptr, int P, int n) {
    const int tid = threadIdx.x;            // 0..127
    const int lane = tid & 63, w = tid >> 6;
    int v = (tid < P) ? bsum[tid] : 0;
    int incl = v;
    #pragma unroll
    for (int d = 1; d < 64; d <<= 1) {
        int o = __shfl_up(incl, d, 64);
        if (lane >= d) incl += o;
    }
    __shared__ int wtot[2];
    if (lane == 63) wtot[w] = incl;
    __syncthreads();
    int off = (w == 1) ? wtot[0] : 0;
    if (tid < P) psum[tid] = off + incl - v;
    if (tid == 0) row_ptr[n] = wtot[0] + wtot[1];
}

__global__ void scan_local_kernel(const int* __restrict__ cnt, const int* __restrict__ psum,
                                  int* __restrict__ row_ptr, int n) {
    const int tid = threadIdx.x;
    const int lane = tid & 63, w = tid >> 6;
    int base = blockIdx.x * 1024 + tid * 4;
    int v0 = (base     < n) ? cnt[base]     : 0;
    int v1 = (base + 1 < n) ? cnt[base + 1] : 0;
    int v2 = (base + 2 < n) ? cnt[base + 2] : 0;
    int v3 = (base + 3 < n) ? cnt[base + 3] : 0;
    int s = v0 + v1 + v2 + v3;
    int incl = s;
    #pragma unroll
    for (int d = 1; d < 64; d <<= 1) {
        int o = __shfl_up(incl, d, 64);
        if (lane >= d) incl += o;
    }
    __shared__ int ws[4];
    if (lane == 63) ws[w] = incl;
    __syncthreads();
    int off = psum[blockIdx.x];
    for (int j = 0; j < w; ++j) off += ws[j];
    int excl = off + incl - s;
    if (base     < n) row_ptr[base]     = excl;
    if (base + 1 < n) row_ptr[base + 1] = excl + v0;
    if (base + 2 < n) row_ptr[base + 2] = excl + v0 + v1;
    if (base + 3 < n) row_ptr[base + 3] = excl + v0 + v1 + v2;
}

// atomic-free CSR fill: slot = row_ptr[d] + xoff[xcd][d] + rank
__global__ void fill_kernel(const int* __restrict__ src, const int* __restrict__ dst,
                            const int* __restrict__ row_ptr, const unsigned* __restrict__ xoff,
                            const int* __restrict__ posx, int* __restrict__ col, int N, int E) {
    int i = blockIdx.x * blockDim.x + threadIdx.x;
    if (i < E) {
        int d = dst[i];
        unsigned p = (unsigned)posx[i];
        unsigned x = p >> 24, r = p & 0xFFFFFFu;
        col[row_ptr[d] + xoff[(size_t)x * N + d] + r] = src[i];
    }
}

// ---------------- dense compute ----------------

// out[n,:] = (out_norm[n] * x[n,:]) @ W — 64 rows/block, W staged in 2 K-halves.
// OT = float or __half. In-place (out==x, fp32) is safe: block stages its own
// 64 rows to LDS before the epilogue writes.
template <typename OT>
__global__ __launch_bounds__(256, 2) void gemm_kernel(
        const float* __restrict__ x, const float* __restrict__ W,
        const float* __restrict__ out_norm, OT* __restrict__ out, int n) {
    __shared__ float xs[64 * 132];    // +4 pad breaks bank aliasing
    __shared__ float wsm[64 * 128];
    const int tid = threadIdx.x;
    const int row0 = blockIdx.x * 64;

    for (int t = tid; t < 64 * 32; t += 256) {
        int r = t >> 5, c4 = t & 31;
        int gr = row0 + r;
        float4 v = {0.f, 0.f, 0.f, 0.f};
        if (gr < n) {
            v = ((const float4*)(x + (size_t)gr * HDIM))[c4];
            float s = out_norm[gr];
            v.x *= s; v.y *= s; v.z *= s; v.w *= s;
        }
        *(float4*)&xs[r * 132 + c4 * 4] = v;
    }

    const int cg = tid & 15, rg = tid >> 4;
    const int c0 = cg * 8, r0 = rg * 4;
    float acc[4][8] = {};

    for (int kh = 0; kh < 2; ++kh) {
        __syncthreads();
        for (int t = tid; t < 64 * 32; t += 256)
            ((float4*)wsm)[t] = ((const float4*)(W + kh * 64 * HDIM))[t];
        __syncthreads();
        #pragma unroll 2
        for (int kk4 = 0; kk4 < 16; ++kk4) {
            float xr[4][4];
            #pragma unroll
            for (int i = 0; i < 4; ++i)
                *(float4*)&xr[i][0] = *(const float4*)&xs[(r0 + i) * 132 + kh * 64 + kk4 * 4];
            #pragma unroll
            for (int q = 0; q < 4; ++q) {
                float wv[8];
                *(float4*)&wv[0] = *(const float4*)&wsm[(kk4 * 4 + q) * 128 + c0];
                *(float4*)&wv[4] = *(const float4*)&wsm[(kk4 * 4 + q) * 128 + c0 + 4];
                #pragma unroll
                for (int i = 0; i < 4; ++i)
                    #pragma unroll
                    for (int j = 0; j < 8; ++j)
                        acc[i][j] = fmaf(xr[i][q], wv[j], acc[i][j]);
            }
        }
    }

    #pragma unroll
    for (int i = 0; i < 4; ++i) {
        int gr = row0 + r0 + i;
        if (gr < n) {
            if constexpr (sizeof(OT) == 2) {
                __half2 p[4];
                #pragma unroll
                for (int q = 0; q < 4; ++q) {
                    __half2 t2;
                    t2.x = __float2half(acc[i][2 * q]);
                    t2.y = __float2half(acc[i][2 * q + 1]);
                    p[q] = t2;
                }
                *(float4*)((__half*)out + (size_t)gr * HDIM + c0) = *(float4*)p;
            } else {
                float4 v0 = {acc[i][0], acc[i][1], acc[i][2], acc[i][3]};
                float4 v1 = {acc[i][4], acc[i][5], acc[i][6], acc[i][7]};
                float4* op = (float4*)((float*)out + (size_t)gr * HDIM + c0);
                op[0] = v0; op[1] = v1;
            }
        }
    }
}

// fp16 gather: one wave/node, 4 edges per wave-load (16 lanes x 16 B), fp32 accum.
__global__ __launch_bounds__(256) void agg_h_kernel(
        const __half* __restrict__ t, const int* __restrict__ row_ptr,
        const int* __restrict__ col, const float* __restrict__ in_norm,
        const float* __restrict__ bias, float* __restrict__ h, int n) {
    int node = blockIdx.x * 4 + (threadIdx.x >> 6);
    if (node >= n) return;
    const int lane = threadIdx.x & 63;
    const int eg = lane >> 4;       // edge group 0..3
    const int fq = lane & 15;       // feature quarter: halfs [fq*8, fq*8+8)
    const int beg = row_ptr[node], end = row_ptr[node + 1];
    float acc0[8] = {}, acc1[8] = {};
    for (int e = beg; e < end; e += 64) {
        int cnt = min(64, end - e);
        int ci = (lane < cnt) ? col[e + lane] : 0;
        for (int j = 0; j < cnt; j += 8) {
            int s0 = __shfl(ci, j + eg, 64);
            int s1 = __shfl(ci, j + 4 + eg, 64);
            float4 r0 = {0.f, 0.f, 0.f, 0.f}, r1 = {0.f, 0.f, 0.f, 0.f};
            if (j + eg < cnt)     r0 = ((const float4*)(t + (size_t)s0 * HDIM))[fq];
            if (j + 4 + eg < cnt) r1 = ((const float4*)(t + (size_t)s1 * HDIM))[fq];
            const __half2* p0 = (const __half2*)&r0;
            const __half2* p1 = (const __half2*)&r1;
            #pragma unroll
            for (int q = 0; q < 4; ++q) {
                float2 f0 = __half22float2(p0[q]);
                float2 f1 = __half22float2(p1[q]);
                acc0[2 * q]     += f0.x; acc0[2 * q + 1] += f0.y;
                acc1[2 * q]     += f1.x; acc1[2 * q + 1] += f1.y;
            }
        }
    }
    #pragma unroll
    for (int q = 0; q < 8; ++q) acc0[q] += acc1[q];
    #pragma unroll
    for (int q = 0; q < 8; ++q) acc0[q] += __shfl_xor(acc0[q], 16, 64);
    #pragma unroll
    for (int q = 0; q < 8; ++q) acc0[q] += __shfl_xor(acc0[q], 32, 64);
    if (eg == 0) {   // lanes 0..15 hold totals for features [fq*8, fq*8+8)
        float inn = in_norm[node];
        float4 b0 = ((const float4*)bias)[2 * fq];
        float4 b1 = ((const float4*)bias)[2 * fq + 1];
        float4 o0, o1;
        o0.x = fmaxf(acc0[0] * inn + b0.x, 0.f);
        o0.y = fmaxf(acc0[1] * inn + b0.y, 0.f);
        o0.z = fmaxf(acc0[2] * inn + b0.z, 0.f);
        o0.w = fmaxf(acc0[3] * inn + b0.w, 0.f);
        o1.x = fmaxf(acc0[4] * inn + b1.x, 0.f);
        o1.y = fmaxf(acc0[5] * inn + b1.y, 0.f);
        o1.z = fmaxf(acc0[6] * inn + b1.z, 0.f);
        o1.w = fmaxf(acc0[7] * inn + b1.w, 0.f);
        float4* op = (float4*)(h + (size_t)node * HDIM);
        op[2 * fq] = o0;
        op[2 * fq + 1] = o1;
    }
}

// fp32 gather (layer 3): one wave/node, half-wave per edge, float4 lanes.
__global__ __launch_bounds__(256) void agg_kernel(
        const float* __restrict__ t, const int* __restrict__ row_ptr,
        const int* __restrict__ col, const float* __restrict__ in_norm,
        const float* __restrict__ bias, float* __restrict__ h, int n) {
    int node = blockIdx.x * 4 + (threadIdx.x >> 6);
    if (node >= n) return;
    const int lane = threadIdx.x & 63;
    const int half = lane >> 5;
    const int fl = lane & 31;
    const int beg = row_ptr[node], end = row_ptr[node + 1];
    float4 acc0 = {0.f, 0.f, 0.f, 0.f}, acc1 = {0.f, 0.f, 0.f, 0.f};
    for (int e = beg; e < end; e += 64) {
        int cnt = min(64, end - e);
        int ci = (lane < cnt) ? col[e + lane] : 0;
        int j = 0;
        for (; j + 3 < cnt; j += 4) {
            int s0 = __shfl(ci, j + half, 64);
            int s1 = __shfl(ci, j + 2 + half, 64);
            float4 v0 = ((const float4*)(t + (size_t)s0 * HDIM))[fl];
            float4 v1 = ((const float4*)(t + (size_t)s1 * HDIM))[fl];
            acc0.x += v0.x; acc0.y += v0.y; acc0.z += v0.z; acc0.w += v0.w;
            acc1.x += v1.x; acc1.y += v1.y; acc1.z += v1.z; acc1.w += v1.w;
        }
        for (; j + 1 < cnt; j += 2) {
            int s0 = __shfl(ci, j + half, 64);
            float4 v0 = ((const float4*)(t + (size_t)s0 * HDIM))[fl];
            acc0.x += v0.x; acc0.y += v0.y; acc0.z += v0.z; acc0.w += v0.w;
        }
        if (j < cnt) {
            int s0 = __shfl(ci, j, 64);
            if (half == 0) {
                float4 v0 = ((const float4*)(t + (size_t)s0 * HDIM))[fl];
                acc0.x += v0.x; acc0.y += v0.y; acc0.z += v0.z; acc0.w += v0.w;
            }
        }
    }
    acc0.x += acc1.x; acc0.y += acc1.y; acc0.z += acc1.z; acc0.w += acc1.w;
    float ox = __shfl(acc0.x, fl + 32, 64);
    float oy = __shfl(acc0.y, fl + 32, 64);
    float oz = __shfl(acc0.z, fl + 32, 64);
    float ow = __shfl(acc0.w, fl + 32, 64);
    if (half == 0) {
        float inn = in_norm[node];
        float4 bb = ((const float4*)bias)[fl];
        float4 res;
        res.x = fmaxf((acc0.x + ox) * inn + bb.x, 0.f);
        res.y = fmaxf((acc0.y + oy) * inn + bb.y, 0.f);
        res.z = fmaxf((acc0.z + oz) * inn + bb.z, 0.f);
        res.w = fmaxf((acc0.w + ow) * inn + bb.w, 0.f);
        ((float4*)(h + (size_t)node * HDIM))[fl] = res;
    }
}

// column sums of h (for mean over nodes)
__global__ void colsum_kernel(const float* __restrict__ h, float* __restrict__ colsum, int n) {
    int c = threadIdx.x & 127;
    int rstart = blockIdx.x * 2 + (threadIdx.x >> 7);
    float s = 0.f;
    for (int r = rstart; r < n; r += gridDim.x * 2)
        s += h[(size_t)r * HDIM + c];
    atomicAdd(&colsum[c], s);
}

__global__ void seg_kernel(const float* __restrict__ colsum, const float* __restrict__ Wp,
                           const float* __restrict__ bp, float* __restrict__ segout, float inv_n) {
    int c = threadIdx.x;
    if (c < NCLS) {
        float s = 0.f;
        #pragma unroll 4
        for (int k = 0; k < HDIM; ++k) s = fmaf(colsum[k], Wp[c * HDIM + k], s);
        segout[c] = s * inv_n + bp[c];
    }
}

// CAM[c, n] = dot(Wp[c,:], h[n,:]) — 64 nodes/block, 10 classes/wave.
__global__ __launch_bounds__(256) void cam_kernel(
        const float* __restrict__ h, const float* __restrict__ Wp,
        float* __restrict__ out, int n) {
    __shared__ float hs[64][132];
    __shared__ float wp[NCLS * HDIM];
    const int tid = threadIdx.x;
    const int n0 = blockIdx.x * 64;
    for (int t = tid; t < NCLS * 32; t += 256)
        ((float4*)wp)[t] = ((const float4*)Wp)[t];
    for (int t = tid; t < 64 * 32; t += 256) {
        int r = t >> 5, c4 = t & 31;
        float4 v = {0.f, 0.f, 0.f, 0.f};
        if (n0 + r < n) v = ((const float4*)(h + (size_t)(n0 + r) * HDIM))[c4];
        *(float4*)&hs[r][c4 * 4] = v;
    }
    __syncthreads();
    const int nl = tid & 63;
    const int cb = (tid >> 6) * 10;
    float acc[10] = {};
    for (int k = 0; k < HDIM; k += 4) {
        float4 hv = *(const float4*)&hs[nl][k];
        #pragma unroll
        for (int c = 0; c < 10; ++c) {
            float4 wv = *(const float4*)&wp[(cb + c) * HDIM + k];
            acc[c] = fmaf(hv.x, wv.x, acc[c]);
            acc[c] = fmaf(hv.y, wv.y, acc[c]);
            acc[c] = fmaf(hv.z, wv.z, acc[c]);
            acc[c] = fmaf(hv.w, wv.w, acc[c]);
        }
    }
    int gn = n0 + nl;
    if (gn < n) {
        #pragma unroll
        for (int c = 0; c < 10; ++c)
            out[(size_t)(cb + c) * n + gn] = acc[c];
    }
}

// ---------------- launch ----------------

extern "C" void kernel_launch(void* const* d_in, const int* in_sizes, int n_in,
                              void* d_out, int out_size, void* d_ws, size_t ws_size,
                              hipStream_t stream) {
    const float* features = (const float*)d_in[0];
    const float* W1 = (const float*)d_in[1];
    const float* b1 = (const float*)d_in[2];
    const float* W2 = (const float*)d_in[3];
    const float* b2 = (const float*)d_in[4];
    const float* W3 = (const float*)d_in[5];
    const float* b3 = (const float*)d_in[6];
    const float* Wp = (const float*)d_in[7];
    const float* bp = (const float*)d_in[8];
    const int*   src = (const int*)d_in[9];
    const int*   dst = (const int*)d_in[10];

    const int N = in_sizes[0] / HDIM;
    const int E = in_sizes[9];
    float* out = (float*)d_out;

    // workspace carve-up
    char* ws = (char*)d_ws;
    size_t off = 0;
    unsigned* hist_out = (unsigned*)(ws + off); off += (size_t)NXCD * N * 4;   // 3.2 MB
    unsigned* hist_in  = (unsigned*)(ws + off); off += (size_t)NXCD * N * 4;   // 3.2 MB
    float* colsum = (float*)(ws + off); off += 128 * 4;
    int* bsum     = (int*)(ws + off); off += 128 * 4;
    int* psum     = (int*)(ws + off); off += 128 * 4;
    int* in_deg   = (int*)(ws + off); off += (size_t)N * 4;
    unsigned* xoff = (unsigned*)(ws + off); off += (size_t)NXCD * N * 4;       // 3.2 MB
    int* row_ptr  = (int*)(ws + off); off += ((size_t)N + 1) * 4; off = (off + 15) & ~(size_t)15;
    int* col_idx  = (int*)(ws + off); off += (size_t)E * 4; off = (off + 15) & ~(size_t)15;
    float* out_norm = (float*)(ws + off); off += (size_t)N * 4;
    float* in_norm  = (float*)(ws + off); off += (size_t)N * 4; off = (off + 255) & ~(size_t)255;
    __half* Bh = (__half*)(ws + off); off += (size_t)N * HDIM * 2; off = (off + 255) & ~(size_t)255;
    float* F0 = (float*)(ws + off); off += (size_t)N * HDIM * 4;
    float* F1 = (float*)(ws + off); off += (size_t)N * HDIM * 4;
    (void)ws_size; (void)n_in; (void)out_size;

    int* posx = (int*)F1;   // F1 unused until layer-3 agg; reuse for posx[E]

    // zero hist_out, hist_in, colsum (contiguous region)
    const int nzero4 = (2 * NXCD * N + 128 + 3) / 4;
    zero4_kernel<<<(nzero4 + 255) / 256, 256, 0, stream>>>((int4*)ws, nzero4);
    deg_kernel<<<(E + 255) / 256, 256, 0, stream>>>(src, dst, hist_out, hist_in, posx, N, E);
    xcdscan_kernel<<<(N + 255) / 256, 256, 0, stream>>>(hist_out, hist_in, xoff, in_deg,
                                                        out_norm, in_norm, N);

    const int P = (N + 1023) / 1024;   // <= 128
    scan_part_kernel<<<P, 256, 0, stream>>>(in_deg, bsum, N);
    scan_mid_kernel<<<1, 128, 0, stream>>>(bsum, psum, row_ptr, P, N);
    scan_local_kernel<<<P, 256, 0, stream>>>(in_deg, psum, row_ptr, N);

    fill_kernel<<<(E + 255) / 256, 256, 0, stream>>>(src, dst, row_ptr, xoff, posx, col_idx, N, E);

    const int gemm_blocks = (N + 63) / 64;
    const int agg_blocks  = (N + 3) / 4;

    // layer 1 (fp16 gather tensor)
    gemm_kernel<__half><<<gemm_blocks, 256, 0, stream>>>(features, W1, out_norm, Bh, N);
    agg_h_kernel<<<agg_blocks, 256, 0, stream>>>(Bh, row_ptr, col_idx, in_norm, b1, F0, N);
    // layer 2 (fp16 gather tensor)
    gemm_kernel<__half><<<gemm_blocks, 256, 0, stream>>>(F0, W2, out_norm, Bh, N);
    agg_h_kernel<<<agg_blocks, 256, 0, stream>>>(Bh, row_ptr, col_idx, in_norm, b2, F0, N);
    // layer 3 (fp32, gemm in-place on F0)
    gemm_kernel<float><<<gemm_blocks, 256, 0, stream>>>(F0, W3, out_norm, F0, N);
    agg_kernel<<<agg_blocks, 256, 0, stream>>>(F0, row_ptr, col_idx, in_norm, b3, F1, N);

    // head (reads h3 = F1)
    colsum_kernel<<<512, 256, 0, stream>>>(F1, colsum, N);
    seg_kernel<<<1, 64, 0, stream>>>(colsum, Wp, bp, out, 1.0f / (float)N);
    cam_kernel<<<(N + 63) / 64, 256, 0, stream>>>(F1, Wp, out + NCLS, N);
}

// Round 5
// 658.901 us; speedup vs baseline: 1.2252x; 1.2252x over previous
//
#include <hip/hip_runtime.h>
#include <hip/hip_bf16.h>
#include <hip/hip_fp16.h>

// GCN: 3 layers of  h = relu(in_norm * A_pull( (out_norm*x) @ W ) + b)
// then seg_output = (mean_n h3) @ Wp^T + bp  and  CAM = Wp @ h3^T.
// CSR built per call (deg atomics yield per-edge slot -> fill atomic-free).
// GEMMs run on MFMA f16 (fp32 accum), gather tensor is fp16 for all layers;
// h (agg output) and the CAM/seg head stay fp32.

#define HDIM 128
#define NCLS 40

typedef _Float16 half8 __attribute__((ext_vector_type(8)));
typedef float f32x4 __attribute__((ext_vector_type(4)));

// ---------------- graph preprocessing ----------------

__global__ void zero_kernel(int* __restrict__ p, int n) {
    int i = blockIdx.x * blockDim.x + threadIdx.x;
    if (i < n) p[i] = 0;
}

// 1 edge/thread; pos = rank of edge within its dst row.
__global__ void deg_kernel(const int* __restrict__ src, const int* __restrict__ dst,
                           int* __restrict__ out_deg, int* __restrict__ in_deg,
                           int* __restrict__ pos, int E) {
    int i = blockIdx.x * blockDim.x + threadIdx.x;
    if (i < E) {
        atomicAdd(&out_deg[src[i]], 1);
        pos[i] = atomicAdd(&in_deg[dst[i]], 1);
    }
}

__global__ void norm_kernel(const int* __restrict__ out_deg, const int* __restrict__ in_deg,
                            float* __restrict__ out_norm, float* __restrict__ in_norm, int n) {
    int i = blockIdx.x * blockDim.x + threadIdx.x;
    if (i < n) {
        out_norm[i] = 1.0f / sqrtf((float)max(out_deg[i], 1));
        in_norm[i]  = 1.0f / sqrtf((float)max(in_deg[i], 1));
    }
}

// ---- 3-pass exclusive scan over in_deg -> row_ptr ----

__global__ void scan_part_kernel(const int* __restrict__ cnt, int* __restrict__ bsum, int n) {
    const int tid = threadIdx.x;
    int base = blockIdx.x * 1024 + tid * 4;
    int s = 0;
    #pragma unroll
    for (int j = 0; j < 4; ++j) if (base + j < n) s += cnt[base + j];
    #pragma unroll
    for (int d = 1; d < 64; d <<= 1) s += __shfl_down(s, d, 64);
    __shared__ int ws[4];
    if ((tid & 63) == 0) ws[tid >> 6] = s;
    __syncthreads();
    if (tid == 0) bsum[blockIdx.x] = ws[0] + ws[1] + ws[2] + ws[3];
}

__global__ void scan_mid_kernel(const int* __restrict__ bsum, int* __restrict__ psum,
                                int* __restrict__ row_ptr, int P, int n) {
    const int tid = threadIdx.x;            // 0..127
    const int lane = tid & 63, w = tid >> 6;
    int v = (tid < P) ? bsum[tid] : 0;
    int incl = v;
    #pragma unroll
    for (int d = 1; d < 64; d <<= 1) {
        int o = __shfl_up(incl, d, 64);
        if (lane >= d) incl += o;
    }
    __shared__ int wtot[2];
    if (lane == 63) wtot[w] = incl;
    __syncthreads();
    int off = (w == 1) ? wtot[0] : 0;
    if (tid < P) psum[tid] = off + incl - v;
    if (tid == 0) row_ptr[n] = wtot[0] + wtot[1];
}

__global__ void scan_local_kernel(const int* __restrict__ cnt, const int* __restrict__ psum,
                                  int* __restrict__ row_ptr, int n) {
    const int tid = threadIdx.x;
    const int lane = tid & 63, w = tid >> 6;
    int base = blockIdx.x * 1024 + tid * 4;
    int v0 = (base     < n) ? cnt[base]     : 0;
    int v1 = (base + 1 < n) ? cnt[base + 1] : 0;
    int v2 = (base + 2 < n) ? cnt[base + 2] : 0;
    int v3 = (base + 3 < n) ? cnt[base + 3] : 0;
    int s = v0 + v1 + v2 + v3;
    int incl = s;
    #pragma unroll
    for (int d = 1; d < 64; d <<= 1) {
        int o = __shfl_up(incl, d, 64);
        if (lane >= d) incl += o;
    }
    __shared__ int ws[4];
    if (lane == 63) ws[w] = incl;
    __syncthreads();
    int off = psum[blockIdx.x];
    for (int j = 0; j < w; ++j) off += ws[j];
    int excl = off + incl - s;
    if (base     < n) row_ptr[base]     = excl;
    if (base + 1 < n) row_ptr[base + 1] = excl + v0;
    if (base + 2 < n) row_ptr[base + 2] = excl + v0 + v1;
    if (base + 3 < n) row_ptr[base + 3] = excl + v0 + v1 + v2;
}

// atomic-free CSR fill using precomputed pos
__global__ void fill_kernel(const int* __restrict__ src, const int* __restrict__ dst,
                            const int* __restrict__ row_ptr, const int* __restrict__ pos,
                            int* __restrict__ col, int E) {
    int i = blockIdx.x * blockDim.x + threadIdx.x;
    if (i < E)
        col[row_ptr[dst[i]] + pos[i]] = src[i];
}

// ---------------- dense compute ----------------

// WT[w][n][k] = (fp16) W_w[k][n] for w = 0..2
__global__ void convw_kernel(const float* __restrict__ W1, const float* __restrict__ W2,
                             const float* __restrict__ W3, _Float16* __restrict__ WT) {
    int i = blockIdx.x * blockDim.x + threadIdx.x;   // 0 .. 3*16384
    if (i < 3 * HDIM * HDIM) {
        int w = i >> 14, r = i & (HDIM * HDIM - 1);
        int nn = r >> 7, k = r & 127;
        const float* W = (w == 0) ? W1 : (w == 1) ? W2 : W3;
        WT[i] = (_Float16)W[k * HDIM + nn];
    }
}

// out[m,:] = fp16( (out_norm[m] * x[m,:]) @ W )  via mfma_f32_16x16x32_f16.
// Block = 4 waves = 64 rows; wave handles 16 rows x all 128 cols (8 n-tiles).
// B-frags read from global WT (32 KB, L2-resident). Output staged via LDS.
__global__ __launch_bounds__(256) void gemm_mfma_kernel(
        const float* __restrict__ x, const _Float16* __restrict__ WT,
        const float* __restrict__ out_norm, _Float16* __restrict__ out, int n) {
    __shared__ _Float16 cs[64][136];
    const int tid = threadIdx.x;
    const int wave = tid >> 6, lane = tid & 63;
    const int quad = lane >> 4, cI = lane & 15;
    const int row0 = blockIdx.x * 64;
    const int gm = row0 + wave * 16 + cI;
    const int gmc = min(gm, n - 1);                 // clamp: no OOB reads
    const float norm = out_norm[gmc];

    // A fragments: a[kc][j] = xn[m = cI][k = kc*32 + quad*8 + j]
    const float* xr = x + (size_t)gmc * HDIM;
    half8 afr[4];
    #pragma unroll
    for (int kc = 0; kc < 4; ++kc) {
        float4 u = *(const float4*)(xr + kc * 32 + quad * 8);
        float4 v = *(const float4*)(xr + kc * 32 + quad * 8 + 4);
        half8 t;
        t[0] = (_Float16)(u.x * norm); t[1] = (_Float16)(u.y * norm);
        t[2] = (_Float16)(u.z * norm); t[3] = (_Float16)(u.w * norm);
        t[4] = (_Float16)(v.x * norm); t[5] = (_Float16)(v.y * norm);
        t[6] = (_Float16)(v.z * norm); t[7] = (_Float16)(v.w * norm);
        afr[kc] = t;
    }

    f32x4 acc[8];
    #pragma unroll
    for (int nt = 0; nt < 8; ++nt) acc[nt] = (f32x4){0.f, 0.f, 0.f, 0.f};

    #pragma unroll
    for (int nt = 0; nt < 8; ++nt) {
        const _Float16* wb = WT + (size_t)(nt * 16 + cI) * HDIM + quad * 8;
        #pragma unroll
        for (int kc = 0; kc < 4; ++kc) {
            half8 bfr = *(const half8*)(wb + kc * 32);
            acc[nt] = __builtin_amdgcn_mfma_f32_16x16x32_f16(afr[kc], bfr, acc[nt], 0, 0, 0);
        }
    }

    // C/D layout: col = lane&15, row = quad*4 + reg  (within the 16x16 tile)
    #pragma unroll
    for (int nt = 0; nt < 8; ++nt)
        #pragma unroll
        for (int i = 0; i < 4; ++i)
            cs[wave * 16 + quad * 4 + i][nt * 16 + cI] = (_Float16)acc[nt][i];
    __syncthreads();

    for (int t2 = tid; t2 < 64 * 16; t2 += 256) {
        int r = t2 >> 4, s = t2 & 15;
        int gr = row0 + r;
        if (gr < n)
            *(float4*)(out + (size_t)gr * HDIM + s * 8) = *(float4*)&cs[r][s * 8];
    }
}

// fp16 gather: h[n,:] = relu(in_norm[n]*sum t[col[e],:] + b) — one wave/node,
// 4 edges per wave-load (16 lanes x 16 B = one 256-B fp16 row), fp32 accum.
__global__ __launch_bounds__(256) void agg_h_kernel(
        const _Float16* __restrict__ t, const int* __restrict__ row_ptr,
        const int* __restrict__ col, const float* __restrict__ in_norm,
        const float* __restrict__ bias, float* __restrict__ h, int n) {
    int node = blockIdx.x * 4 + (threadIdx.x >> 6);
    if (node >= n) return;
    const int lane = threadIdx.x & 63;
    const int eg = lane >> 4;       // edge group 0..3
    const int fq = lane & 15;       // feature quarter: halfs [fq*8, fq*8+8)
    const int beg = row_ptr[node], end = row_ptr[node + 1];
    float acc0[8] = {}, acc1[8] = {};
    for (int e = beg; e < end; e += 64) {
        int cnt = min(64, end - e);
        int ci = (lane < cnt) ? col[e + lane] : 0;
        for (int j = 0; j < cnt; j += 8) {
            int s0 = __shfl(ci, j + eg, 64);
            int s1 = __shfl(ci, j + 4 + eg, 64);
            float4 r0 = {0.f, 0.f, 0.f, 0.f}, r1 = {0.f, 0.f, 0.f, 0.f};
            if (j + eg < cnt)     r0 = ((const float4*)(t + (size_t)s0 * HDIM))[fq];
            if (j + 4 + eg < cnt) r1 = ((const float4*)(t + (size_t)s1 * HDIM))[fq];
            const __half2* p0 = (const __half2*)&r0;
            const __half2* p1 = (const __half2*)&r1;
            #pragma unroll
            for (int q = 0; q < 4; ++q) {
                float2 f0 = __half22float2(p0[q]);
                float2 f1 = __half22float2(p1[q]);
                acc0[2 * q]     += f0.x; acc0[2 * q + 1] += f0.y;
                acc1[2 * q]     += f1.x; acc1[2 * q + 1] += f1.y;
            }
        }
    }
    #pragma unroll
    for (int q = 0; q < 8; ++q) acc0[q] += acc1[q];
    #pragma unroll
    for (int q = 0; q < 8; ++q) acc0[q] += __shfl_xor(acc0[q], 16, 64);
    #pragma unroll
    for (int q = 0; q < 8; ++q) acc0[q] += __shfl_xor(acc0[q], 32, 64);
    if (eg == 0) {   // lanes 0..15 hold totals for features [fq*8, fq*8+8)
        float inn = in_norm[node];
        float4 b0 = ((const float4*)bias)[2 * fq];
        float4 b1 = ((const float4*)bias)[2 * fq + 1];
        float4 o0, o1;
        o0.x = fmaxf(acc0[0] * inn + b0.x, 0.f);
        o0.y = fmaxf(acc0[1] * inn + b0.y, 0.f);
        o0.z = fmaxf(acc0[2] * inn + b0.z, 0.f);
        o0.w = fmaxf(acc0[3] * inn + b0.w, 0.f);
        o1.x = fmaxf(acc0[4] * inn + b1.x, 0.f);
        o1.y = fmaxf(acc0[5] * inn + b1.y, 0.f);
        o1.z = fmaxf(acc0[6] * inn + b1.z, 0.f);
        o1.w = fmaxf(acc0[7] * inn + b1.w, 0.f);
        float4* op = (float4*)(h + (size_t)node * HDIM);
        op[2 * fq] = o0;
        op[2 * fq + 1] = o1;
    }
}

// column sums of h (for mean over nodes)
__global__ void colsum_kernel(const float* __restrict__ h, float* __restrict__ colsum, int n) {
    int c = threadIdx.x & 127;
    int rstart = blockIdx.x * 2 + (threadIdx.x >> 7);
    float s = 0.f;
    for (int r = rstart; r < n; r += gridDim.x * 2)
        s += h[(size_t)r * HDIM + c];
    atomicAdd(&colsum[c], s);
}

__global__ void seg_kernel(const float* __restrict__ colsum, const float* __restrict__ Wp,
                           const float* __restrict__ bp, float* __restrict__ segout, float inv_n) {
    int c = threadIdx.x;
    if (c < NCLS) {
        float s = 0.f;
        #pragma unroll 4
        for (int k = 0; k < HDIM; ++k) s = fmaf(colsum[k], Wp[c * HDIM + k], s);
        segout[c] = s * inv_n + bp[c];
    }
}

// CAM[c, n] = dot(Wp[c,:], h[n,:]) — 64 nodes/block, 10 classes/wave.
__global__ __launch_bounds__(256) void cam_kernel(
        const float* __restrict__ h, const float* __restrict__ Wp,
        float* __restrict__ out, int n) {
    __shared__ float hs[64][132];
    __shared__ float wp[NCLS * HDIM];
    const int tid = threadIdx.x;
    const int n0 = blockIdx.x * 64;
    for (int t = tid; t < NCLS * 32; t += 256)
        ((float4*)wp)[t] = ((const float4*)Wp)[t];
    for (int t = tid; t < 64 * 32; t += 256) {
        int r = t >> 5, c4 = t & 31;
        float4 v = {0.f, 0.f, 0.f, 0.f};
        if (n0 + r < n) v = ((const float4*)(h + (size_t)(n0 + r) * HDIM))[c4];
        *(float4*)&hs[r][c4 * 4] = v;
    }
    __syncthreads();
    const int nl = tid & 63;
    const int cb = (tid >> 6) * 10;
    float acc[10] = {};
    for (int k = 0; k < HDIM; k += 4) {
        float4 hv = *(const float4*)&hs[nl][k];
        #pragma unroll
        for (int c = 0; c < 10; ++c) {
            float4 wv = *(const float4*)&wp[(cb + c) * HDIM + k];
            acc[c] = fmaf(hv.x, wv.x, acc[c]);
            acc[c] = fmaf(hv.y, wv.y, acc[c]);
            acc[c] = fmaf(hv.z, wv.z, acc[c]);
            acc[c] = fmaf(hv.w, wv.w, acc[c]);
        }
    }
    int gn = n0 + nl;
    if (gn < n) {
        #pragma unroll
        for (int c = 0; c < 10; ++c)
            out[(size_t)(cb + c) * n + gn] = acc[c];
    }
}

// ---------------- launch ----------------

extern "C" void kernel_launch(void* const* d_in, const int* in_sizes, int n_in,
                              void* d_out, int out_size, void* d_ws, size_t ws_size,
                              hipStream_t stream) {
    const float* features = (const float*)d_in[0];
    const float* W1 = (const float*)d_in[1];
    const float* b1 = (const float*)d_in[2];
    const float* W2 = (const float*)d_in[3];
    const float* b2 = (const float*)d_in[4];
    const float* W3 = (const float*)d_in[5];
    const float* b3 = (const float*)d_in[6];
    const float* Wp = (const float*)d_in[7];
    const float* bp = (const float*)d_in[8];
    const int*   src = (const int*)d_in[9];
    const int*   dst = (const int*)d_in[10];

    const int N = in_sizes[0] / HDIM;
    const int E = in_sizes[9];
    float* out = (float*)d_out;

    // workspace carve-up
    char* ws = (char*)d_ws;
    size_t off = 0;
    int* out_deg  = (int*)(ws + off); off += (size_t)N * 4;
    int* in_deg   = (int*)(ws + off); off += (size_t)N * 4;
    float* colsum = (float*)(ws + off); off += 128 * 4;
    int* bsum     = (int*)(ws + off); off += 128 * 4;
    int* psum     = (int*)(ws + off); off += 128 * 4;
    int* row_ptr  = (int*)(ws + off); off += ((size_t)N + 1) * 4; off = (off + 15) & ~(size_t)15;
    int* col_idx  = (int*)(ws + off); off += (size_t)E * 4; off = (off + 15) & ~(size_t)15;
    float* out_norm = (float*)(ws + off); off += (size_t)N * 4;
    float* in_norm  = (float*)(ws + off); off += (size_t)N * 4; off = (off + 255) & ~(size_t)255;
    _Float16* WT = (_Float16*)(ws + off); off += 3 * HDIM * HDIM * 2; off = (off + 255) & ~(size_t)255;
    _Float16* Bh = (_Float16*)(ws + off); off += (size_t)N * HDIM * 2; off = (off + 255) & ~(size_t)255;
    float* F0 = (float*)(ws + off); off += (size_t)N * HDIM * 4;
    float* F1 = (float*)(ws + off); off += (size_t)N * HDIM * 4;
    (void)ws_size; (void)n_in; (void)out_size;

    int* pos = (int*)F1;   // F1 unused until layer-3 agg; reuse for pos[E]

    const int nzero = 2 * N + 128;
    zero_kernel<<<(nzero + 255) / 256, 256, 0, stream>>>((int*)ws, nzero);
    deg_kernel<<<(E + 255) / 256, 256, 0, stream>>>(src, dst, out_deg, in_deg, pos, E);
    norm_kernel<<<(N + 255) / 256, 256, 0, stream>>>(out_deg, in_deg, out_norm, in_norm, N);

    const int P = (N + 1023) / 1024;   // <= 128
    scan_part_kernel<<<P, 256, 0, stream>>>(in_deg, bsum, N);
    scan_mid_kernel<<<1, 128, 0, stream>>>(bsum, psum, row_ptr, P, N);
    scan_local_kernel<<<P, 256, 0, stream>>>(in_deg, psum, row_ptr, N);

    fill_kernel<<<(E + 255) / 256, 256, 0, stream>>>(src, dst, row_ptr, pos, col_idx, E);

    convw_kernel<<<(3 * HDIM * HDIM + 255) / 256, 256, 0, stream>>>(W1, W2, W3, WT);

    const int gemm_blocks = (N + 63) / 64;
    const int agg_blocks  = (N + 3) / 4;

    // layer 1
    gemm_mfma_kernel<<<gemm_blocks, 256, 0, stream>>>(features, WT, out_norm, Bh, N);
    agg_h_kernel<<<agg_blocks, 256, 0, stream>>>(Bh, row_ptr, col_idx, in_norm, b1, F0, N);
    // layer 2
    gemm_mfma_kernel<<<gemm_blocks, 256, 0, stream>>>(F0, WT + HDIM * HDIM, out_norm, Bh, N);
    agg_h_kernel<<<agg_blocks, 256, 0, stream>>>(Bh, row_ptr, col_idx, in_norm, b2, F0, N);
    // layer 3
    gemm_mfma_kernel<<<gemm_blocks, 256, 0, stream>>>(F0, WT + 2 * HDIM * HDIM, out_norm, Bh, N);
    agg_h_kernel<<<agg_blocks, 256, 0, stream>>>(Bh, row_ptr, col_idx, in_norm, b3, F1, N);

    // head (reads h3 = F1)
    colsum_kernel<<<512, 256, 0, stream>>>(F1, colsum, N);
    seg_kernel<<<1, 64, 0, stream>>>(colsum, Wp, bp, out, 1.0f / (float)N);
    cam_kernel<<<(N + 63) / 64, 256, 0, stream>>>(F1, Wp, out + NCLS, N);
}

// Round 6
// 565.747 us; speedup vs baseline: 1.4269x; 1.1647x over previous
//
#include <hip/hip_runtime.h>
#include <hip/hip_bf16.h>
#include <hip/hip_fp16.h>

// GCN: 3 layers of  h = relu(in_norm * A_pull( (out_norm*x) @ W ) + b)
// then seg_output = (mean_n h3) @ Wp^T + bp  and  CAM = Wp @ h3^T.
// Preprocessing: bucket edges by 512-node ranges (LDS histograms, contiguous
// reservation atomics only — NO scattered global atomics, which write through
// L2 at ~0.7 TB/s of 32B sectors on gfx950 [R1/R2/R4]). Bucket base == CSR
// row base, so build_csr emits row_ptr + col directly.
// Dense: MFMA f16 GEMMs, fp16 gather tensor, fp32 h / head.

#define HDIM 128
#define NCLS 40
#define BSH 9
#define BSZ 512          // nodes per bucket
#define KMAX 256
#define EPB 4096         // edges per scatter/count block

typedef _Float16 half8 __attribute__((ext_vector_type(8)));
typedef float f32x4 __attribute__((ext_vector_type(4)));

// ---------------- graph preprocessing ----------------

__global__ void zero_kernel(int* __restrict__ p, int n) {
    int i = blockIdx.x * blockDim.x + threadIdx.x;
    if (i < n) p[i] = 0;
}

// per-block LDS bucket histograms (dst and src), merged with contiguous atomics
__global__ __launch_bounds__(256) void bucket_count_kernel(
        const int* __restrict__ src, const int* __restrict__ dst,
        int* __restrict__ bcnt, int* __restrict__ sbcnt, int K, int E) {
    __shared__ int lc[KMAX], ls[KMAX];
    const int tid = threadIdx.x;
    lc[tid] = 0; ls[tid] = 0;
    __syncthreads();
    const int base = blockIdx.x * EPB;
    const int lim = min(EPB, E - base);
    for (int i = tid; i < lim; i += 256) {
        atomicAdd(&lc[dst[base + i] >> BSH], 1);
        atomicAdd(&ls[src[base + i] >> BSH], 1);
    }
    __syncthreads();
    if (tid < K) {
        if (lc[tid]) atomicAdd(&bcnt[tid], lc[tid]);
        if (ls[tid]) atomicAdd(&sbcnt[tid], ls[tid]);
    }
}

// single block: exclusive scan of both bucket-count arrays (K <= 256)
__global__ __launch_bounds__(256) void bucket_scan_kernel(
        const int* __restrict__ a, const int* __restrict__ b,
        int* __restrict__ abase, int* __restrict__ bbase, int K) {
    __shared__ int ws[8];
    const int tid = threadIdx.x, lane = tid & 63, w = tid >> 6;
    int va = (tid < K) ? a[tid] : 0;
    int vb = (tid < K) ? b[tid] : 0;
    int ia = va, ib = vb;
    #pragma unroll
    for (int d = 1; d < 64; d <<= 1) {
        int oa = __shfl_up(ia, d, 64);
        int ob = __shfl_up(ib, d, 64);
        if (lane >= d) { ia += oa; ib += ob; }
    }
    if (lane == 63) { ws[w] = ia; ws[4 + w] = ib; }
    __syncthreads();
    int oa = 0, ob = 0;
    for (int j = 0; j < w; ++j) { oa += ws[j]; ob += ws[4 + j]; }
    if (tid < K) { abase[tid] = oa + ia - va; bbase[tid] = ob + ib - vb; }
    if (tid == K - 1) { abase[K] = oa + ia; bbase[K] = ob + ib; }
}

// re-count in LDS, reserve contiguous runs, write bucketed records
__global__ __launch_bounds__(256) void bucket_scatter_kernel(
        const int* __restrict__ src, const int* __restrict__ dst,
        const int* __restrict__ bbase, const int* __restrict__ sbase,
        int* __restrict__ bcur, int* __restrict__ scur,
        int2* __restrict__ dbuf, int* __restrict__ sbuf, int K, int E) {
    __shared__ int lc[KMAX], lb[KMAX], ls[KMAX], lsb[KMAX];
    const int tid = threadIdx.x;
    lc[tid] = 0; ls[tid] = 0;
    __syncthreads();
    const int base = blockIdx.x * EPB;
    const int lim = min(EPB, E - base);
    for (int i = tid; i < lim; i += 256) {
        atomicAdd(&lc[dst[base + i] >> BSH], 1);
        atomicAdd(&ls[src[base + i] >> BSH], 1);
    }
    __syncthreads();
    if (tid < K) {
        lb[tid]  = bbase[tid] + (lc[tid] ? atomicAdd(&bcur[tid], lc[tid]) : 0);
        lsb[tid] = sbase[tid] + (ls[tid] ? atomicAdd(&scur[tid], ls[tid]) : 0);
    }
    __syncthreads();
    lc[tid] = 0; ls[tid] = 0;
    __syncthreads();
    for (int i = tid; i < lim; i += 256) {
        int d = dst[base + i], s = src[base + i];
        int kd = d >> BSH, ks = s >> BSH;
        int r = atomicAdd(&lc[kd], 1);
        dbuf[lb[kd] + r] = make_int2(d, s);
        int r2 = atomicAdd(&ls[ks], 1);
        sbuf[lsb[ks] + r2] = s;
    }
}

// one block per dst-bucket: histogram -> scan -> row_ptr/in_norm -> ranks -> col
__global__ __launch_bounds__(256) void build_csr_kernel(
        const int2* __restrict__ dbuf, const int* __restrict__ bbase,
        int* __restrict__ row_ptr, float* __restrict__ in_norm,
        int* __restrict__ col, int N, int K, int E) {
    __shared__ int cnt[BSZ], lsc[BSZ];
    __shared__ int wsum[4];
    const int k = blockIdx.x, tid = threadIdx.x;
    const int node0 = k << BSH;
    const int beg = bbase[k], end = bbase[k + 1];
    cnt[tid] = 0; cnt[tid + 256] = 0;
    __syncthreads();
    for (int i = beg + tid; i < end; i += 256)
        atomicAdd(&cnt[dbuf[i].x & (BSZ - 1)], 1);
    __syncthreads();
    // exclusive scan of cnt[0..511]; thread owns slots 2t, 2t+1
    const int c0 = cnt[2 * tid], c1 = cnt[2 * tid + 1];
    const int s = c0 + c1;
    int incl = s;
    const int lane = tid & 63, w = tid >> 6;
    #pragma unroll
    for (int d = 1; d < 64; d <<= 1) {
        int o = __shfl_up(incl, d, 64);
        if (lane >= d) incl += o;
    }
    if (lane == 63) wsum[w] = incl;
    __syncthreads();
    int off = 0;
    for (int j = 0; j < w; ++j) off += wsum[j];
    const int excl = off + incl - s;
    lsc[2 * tid] = excl;
    lsc[2 * tid + 1] = excl + c0;
    const int n0 = node0 + 2 * tid, n1 = node0 + 2 * tid + 1;
    if (n0 < N) { row_ptr[n0] = beg + excl;      in_norm[n0] = 1.0f / sqrtf((float)max(c0, 1)); }
    if (n1 < N) { row_ptr[n1] = beg + excl + c0; in_norm[n1] = 1.0f / sqrtf((float)max(c1, 1)); }
    if (k == K - 1 && tid == 0) row_ptr[N] = E;
    __syncthreads();
    cnt[2 * tid] = 0; cnt[2 * tid + 1] = 0;
    __syncthreads();
    for (int i = beg + tid; i < end; i += 256) {
        int2 e = dbuf[i];
        int local = e.x & (BSZ - 1);
        int r = atomicAdd(&cnt[local], 1);
        col[beg + lsc[local] + r] = e.y;
    }
}

// one block per src-bucket: histogram -> out_norm
__global__ __launch_bounds__(256) void outdeg_kernel(
        const int* __restrict__ sbuf, const int* __restrict__ sbase,
        float* __restrict__ out_norm, int N) {
    __shared__ int cnt[BSZ];
    const int k = blockIdx.x, tid = threadIdx.x;
    const int beg = sbase[k], end = sbase[k + 1];
    cnt[tid] = 0; cnt[tid + 256] = 0;
    __syncthreads();
    for (int i = beg + tid; i < end; i += 256)
        atomicAdd(&cnt[sbuf[i] & (BSZ - 1)], 1);
    __syncthreads();
    const int n0 = (k << BSH) + tid, n1 = n0 + 256;
    if (n0 < N) out_norm[n0] = 1.0f / sqrtf((float)max(cnt[tid], 1));
    if (n1 < N) out_norm[n1] = 1.0f / sqrtf((float)max(cnt[tid + 256], 1));
}

// ---------------- dense compute ----------------

// WT[w][n][k] = (fp16) W_w[k][n] for w = 0..2
__global__ void convw_kernel(const float* __restrict__ W1, const float* __restrict__ W2,
                             const float* __restrict__ W3, _Float16* __restrict__ WT) {
    int i = blockIdx.x * blockDim.x + threadIdx.x;   // 0 .. 3*16384
    if (i < 3 * HDIM * HDIM) {
        int w = i >> 14, r = i & (HDIM * HDIM - 1);
        int nn = r >> 7, k = r & 127;
        const float* W = (w == 0) ? W1 : (w == 1) ? W2 : W3;
        WT[i] = (_Float16)W[k * HDIM + nn];
    }
}

// out[m,:] = fp16( (out_norm[m] * x[m,:]) @ W )  via mfma_f32_16x16x32_f16.
__global__ __launch_bounds__(256) void gemm_mfma_kernel(
        const float* __restrict__ x, const _Float16* __restrict__ WT,
        const float* __restrict__ out_norm, _Float16* __restrict__ out, int n) {
    __shared__ _Float16 cs[64][136];
    const int tid = threadIdx.x;
    const int wave = tid >> 6, lane = tid & 63;
    const int quad = lane >> 4, cI = lane & 15;
    const int row0 = blockIdx.x * 64;
    const int gm = row0 + wave * 16 + cI;
    const int gmc = min(gm, n - 1);                 // clamp: no OOB reads
    const float norm = out_norm[gmc];

    const float* xr = x + (size_t)gmc * HDIM;
    half8 afr[4];
    #pragma unroll
    for (int kc = 0; kc < 4; ++kc) {
        float4 u = *(const float4*)(xr + kc * 32 + quad * 8);
        float4 v = *(const float4*)(xr + kc * 32 + quad * 8 + 4);
        half8 t;
        t[0] = (_Float16)(u.x * norm); t[1] = (_Float16)(u.y * norm);
        t[2] = (_Float16)(u.z * norm); t[3] = (_Float16)(u.w * norm);
        t[4] = (_Float16)(v.x * norm); t[5] = (_Float16)(v.y * norm);
        t[6] = (_Float16)(v.z * norm); t[7] = (_Float16)(v.w * norm);
        afr[kc] = t;
    }

    f32x4 acc[8];
    #pragma unroll
    for (int nt = 0; nt < 8; ++nt) acc[nt] = (f32x4){0.f, 0.f, 0.f, 0.f};

    #pragma unroll
    for (int nt = 0; nt < 8; ++nt) {
        const _Float16* wb = WT + (size_t)(nt * 16 + cI) * HDIM + quad * 8;
        #pragma unroll
        for (int kc = 0; kc < 4; ++kc) {
            half8 bfr = *(const half8*)(wb + kc * 32);
            acc[nt] = __builtin_amdgcn_mfma_f32_16x16x32_f16(afr[kc], bfr, acc[nt], 0, 0, 0);
        }
    }

    #pragma unroll
    for (int nt = 0; nt < 8; ++nt)
        #pragma unroll
        for (int i = 0; i < 4; ++i)
            cs[wave * 16 + quad * 4 + i][nt * 16 + cI] = (_Float16)acc[nt][i];
    __syncthreads();

    for (int t2 = tid; t2 < 64 * 16; t2 += 256) {
        int r = t2 >> 4, ss = t2 & 15;
        int gr = row0 + r;
        if (gr < n)
            *(float4*)(out + (size_t)gr * HDIM + ss * 8) = *(float4*)&cs[r][ss * 8];
    }
}

// fp16 gather: h[n,:] = relu(in_norm[n]*sum t[col[e],:] + b) — one wave/node,
// 4 edges per wave-load (16 lanes x 16 B = one 256-B fp16 row), fp32 accum.
__global__ __launch_bounds__(256) void agg_h_kernel(
        const _Float16* __restrict__ t, const int* __restrict__ row_ptr,
        const int* __restrict__ col, const float* __restrict__ in_norm,
        const float* __restrict__ bias, float* __restrict__ h, int n) {
    int node = blockIdx.x * 4 + (threadIdx.x >> 6);
    if (node >= n) return;
    const int lane = threadIdx.x & 63;
    const int eg = lane >> 4;       // edge group 0..3
    const int fq = lane & 15;       // feature quarter: halfs [fq*8, fq*8+8)
    const int beg = row_ptr[node], end = row_ptr[node + 1];
    float acc0[8] = {}, acc1[8] = {};
    for (int e = beg; e < end; e += 64) {
        int cnt = min(64, end - e);
        int ci = (lane < cnt) ? col[e + lane] : 0;
        for (int j = 0; j < cnt; j += 8) {
            int s0 = __shfl(ci, j + eg, 64);
            int s1 = __shfl(ci, j + 4 + eg, 64);
            float4 r0 = {0.f, 0.f, 0.f, 0.f}, r1 = {0.f, 0.f, 0.f, 0.f};
            if (j + eg < cnt)     r0 = ((const float4*)(t + (size_t)s0 * HDIM))[fq];
            if (j + 4 + eg < cnt) r1 = ((const float4*)(t + (size_t)s1 * HDIM))[fq];
            const __half2* p0 = (const __half2*)&r0;
            const __half2* p1 = (const __half2*)&r1;
            #pragma unroll
            for (int q = 0; q < 4; ++q) {
                float2 f0 = __half22float2(p0[q]);
                float2 f1 = __half22float2(p1[q]);
                acc0[2 * q]     += f0.x; acc0[2 * q + 1] += f0.y;
                acc1[2 * q]     += f1.x; acc1[2 * q + 1] += f1.y;
            }
        }
    }
    #pragma unroll
    for (int q = 0; q < 8; ++q) acc0[q] += acc1[q];
    #pragma unroll
    for (int q = 0; q < 8; ++q) acc0[q] += __shfl_xor(acc0[q], 16, 64);
    #pragma unroll
    for (int q = 0; q < 8; ++q) acc0[q] += __shfl_xor(acc0[q], 32, 64);
    if (eg == 0) {   // lanes 0..15 hold totals for features [fq*8, fq*8+8)
        float inn = in_norm[node];
        float4 b0 = ((const float4*)bias)[2 * fq];
        float4 b1 = ((const float4*)bias)[2 * fq + 1];
        float4 o0, o1;
        o0.x = fmaxf(acc0[0] * inn + b0.x, 0.f);
        o0.y = fmaxf(acc0[1] * inn + b0.y, 0.f);
        o0.z = fmaxf(acc0[2] * inn + b0.z, 0.f);
        o0.w = fmaxf(acc0[3] * inn + b0.w, 0.f);
        o1.x = fmaxf(acc0[4] * inn + b1.x, 0.f);
        o1.y = fmaxf(acc0[5] * inn + b1.y, 0.f);
        o1.z = fmaxf(acc0[6] * inn + b1.z, 0.f);
        o1.w = fmaxf(acc0[7] * inn + b1.w, 0.f);
        float4* op = (float4*)(h + (size_t)node * HDIM);
        op[2 * fq] = o0;
        op[2 * fq + 1] = o1;
    }
}

// column sums of h (for mean over nodes)
__global__ void colsum_kernel(const float* __restrict__ h, float* __restrict__ colsum, int n) {
    int c = threadIdx.x & 127;
    int rstart = blockIdx.x * 2 + (threadIdx.x >> 7);
    float s = 0.f;
    for (int r = rstart; r < n; r += gridDim.x * 2)
        s += h[(size_t)r * HDIM + c];
    atomicAdd(&colsum[c], s);
}

__global__ void seg_kernel(const float* __restrict__ colsum, const float* __restrict__ Wp,
                           const float* __restrict__ bp, float* __restrict__ segout, float inv_n) {
    int c = threadIdx.x;
    if (c < NCLS) {
        float s = 0.f;
        #pragma unroll 4
        for (int k = 0; k < HDIM; ++k) s = fmaf(colsum[k], Wp[c * HDIM + k], s);
        segout[c] = s * inv_n + bp[c];
    }
}

// CAM[c, n] = dot(Wp[c,:], h[n,:]) — 64 nodes/block, 10 classes/wave.
__global__ __launch_bounds__(256) void cam_kernel(
        const float* __restrict__ h, const float* __restrict__ Wp,
        float* __restrict__ out, int n) {
    __shared__ float hs[64][132];
    __shared__ float wp[NCLS * HDIM];
    const int tid = threadIdx.x;
    const int n0 = blockIdx.x * 64;
    for (int t = tid; t < NCLS * 32; t += 256)
        ((float4*)wp)[t] = ((const float4*)Wp)[t];
    for (int t = tid; t < 64 * 32; t += 256) {
        int r = t >> 5, c4 = t & 31;
        float4 v = {0.f, 0.f, 0.f, 0.f};
        if (n0 + r < n) v = ((const float4*)(h + (size_t)(n0 + r) * HDIM))[c4];
        *(float4*)&hs[r][c4 * 4] = v;
    }
    __syncthreads();
    const int nl = tid & 63;
    const int cb = (tid >> 6) * 10;
    float acc[10] = {};
    for (int k = 0; k < HDIM; k += 4) {
        float4 hv = *(const float4*)&hs[nl][k];
        #pragma unroll
        for (int c = 0; c < 10; ++c) {
            float4 wv = *(const float4*)&wp[(cb + c) * HDIM + k];
            acc[c] = fmaf(hv.x, wv.x, acc[c]);
            acc[c] = fmaf(hv.y, wv.y, acc[c]);
            acc[c] = fmaf(hv.z, wv.z, acc[c]);
            acc[c] = fmaf(hv.w, wv.w, acc[c]);
        }
    }
    int gn = n0 + nl;
    if (gn < n) {
        #pragma unroll
        for (int c = 0; c < 10; ++c)
            out[(size_t)(cb + c) * n + gn] = acc[c];
    }
}

// ---------------- launch ----------------

extern "C" void kernel_launch(void* const* d_in, const int* in_sizes, int n_in,
                              void* d_out, int out_size, void* d_ws, size_t ws_size,
                              hipStream_t stream) {
    const float* features = (const float*)d_in[0];
    const float* W1 = (const float*)d_in[1];
    const float* b1 = (const float*)d_in[2];
    const float* W2 = (const float*)d_in[3];
    const float* b2 = (const float*)d_in[4];
    const float* W3 = (const float*)d_in[5];
    const float* b3 = (const float*)d_in[6];
    const float* Wp = (const float*)d_in[7];
    const float* bp = (const float*)d_in[8];
    const int*   src = (const int*)d_in[9];
    const int*   dst = (const int*)d_in[10];

    const int N = in_sizes[0] / HDIM;
    const int E = in_sizes[9];
    const int K = (N + BSZ - 1) >> BSH;           // buckets (<=256)
    float* out = (float*)d_out;

    // workspace carve-up
    char* ws = (char*)d_ws;
    size_t off = 0;
    int* bcnt   = (int*)(ws + off); off += KMAX * 4;
    int* sbcnt  = (int*)(ws + off); off += KMAX * 4;
    int* bcur   = (int*)(ws + off); off += KMAX * 4;
    int* scur   = (int*)(ws + off); off += KMAX * 4;
    float* colsum = (float*)(ws + off); off += 128 * 4;
    int* bbase  = (int*)(ws + off); off += (KMAX + 1) * 4;
    int* sbase  = (int*)(ws + off); off += (KMAX + 1) * 4;
    int* row_ptr = (int*)(ws + off); off += ((size_t)N + 1) * 4; off = (off + 15) & ~(size_t)15;
    int* col_idx = (int*)(ws + off); off += (size_t)E * 4; off = (off + 15) & ~(size_t)15;
    float* out_norm = (float*)(ws + off); off += (size_t)N * 4;
    float* in_norm  = (float*)(ws + off); off += (size_t)N * 4; off = (off + 255) & ~(size_t)255;
    _Float16* WT = (_Float16*)(ws + off); off += 3 * HDIM * HDIM * 2; off = (off + 255) & ~(size_t)255;
    _Float16* Bh = (_Float16*)(ws + off); off += (size_t)N * HDIM * 2; off = (off + 255) & ~(size_t)255;
    float* F0 = (float*)(ws + off); off += (size_t)N * HDIM * 4;
    float* F1 = (float*)(ws + off); off += (size_t)N * HDIM * 4;
    (void)ws_size; (void)n_in; (void)out_size;

    // bucket scratch lives inside F1 (consumed before layer-3 agg writes F1)
    int2* dbuf = (int2*)F1;                        // E * 8 B
    int*  sbuf = (int*)((char*)F1 + (size_t)E * 8); // E * 4 B  (<= 51.2 MB total)

    const int NB = (E + EPB - 1) / EPB;

    // zero bcnt/sbcnt/bcur/scur/colsum (contiguous head)
    const int nzero = 4 * KMAX + 128;
    zero_kernel<<<(nzero + 255) / 256, 256, 0, stream>>>((int*)ws, nzero);
    bucket_count_kernel<<<NB, 256, 0, stream>>>(src, dst, bcnt, sbcnt, K, E);
    bucket_scan_kernel<<<1, 256, 0, stream>>>(bcnt, sbcnt, bbase, sbase, K);
    bucket_scatter_kernel<<<NB, 256, 0, stream>>>(src, dst, bbase, sbase, bcur, scur,
                                                  dbuf, sbuf, K, E);
    build_csr_kernel<<<K, 256, 0, stream>>>(dbuf, bbase, row_ptr, in_norm, col_idx, N, K, E);
    outdeg_kernel<<<K, 256, 0, stream>>>(sbuf, sbase, out_norm, N);

    convw_kernel<<<(3 * HDIM * HDIM + 255) / 256, 256, 0, stream>>>(W1, W2, W3, WT);

    const int gemm_blocks = (N + 63) / 64;
    const int agg_blocks  = (N + 3) / 4;

    // layer 1
    gemm_mfma_kernel<<<gemm_blocks, 256, 0, stream>>>(features, WT, out_norm, Bh, N);
    agg_h_kernel<<<agg_blocks, 256, 0, stream>>>(Bh, row_ptr, col_idx, in_norm, b1, F0, N);
    // layer 2
    gemm_mfma_kernel<<<gemm_blocks, 256, 0, stream>>>(F0, WT + HDIM * HDIM, out_norm, Bh, N);
    agg_h_kernel<<<agg_blocks, 256, 0, stream>>>(Bh, row_ptr, col_idx, in_norm, b2, F0, N);
    // layer 3
    gemm_mfma_kernel<<<gemm_blocks, 256, 0, stream>>>(F0, WT + 2 * HDIM * HDIM, out_norm, Bh, N);
    agg_h_kernel<<<agg_blocks, 256, 0, stream>>>(Bh, row_ptr, col_idx, in_norm, b3, F1, N);

    // head (reads h3 = F1)
    colsum_kernel<<<512, 256, 0, stream>>>(F1, colsum, N);
    seg_kernel<<<1, 64, 0, stream>>>(colsum, Wp, bp, out, 1.0f / (float)N);
    cam_kernel<<<(N + 63) / 64, 256, 0, stream>>>(F1, Wp, out + NCLS, N);
}